// Round 15
// baseline (115.844 us; speedup 1.0000x reference)
//
#include <hip/hip_runtime.h>

#define HWD 256
#define NB 2
#define NV 5023
#define NF 2048

// ws layout:
//  frP   @ 0x000000  4096 * 64B = 256 KiB  (16 floats per face, batch-major)
//  vattr @ 0x040000  10046*6*4B = 236 KiB  (region 256 KiB)
//  rFace @ 0x080000  4096 * 64B = 256 KiB  (bucket-ordered, segment-major records)

__device__ __forceinline__ float pix_coord(int i) {
    return ((float)i + 0.5f) * 0.0078125f - 1.0f;   // exact fp32
}

__device__ __forceinline__ int z_bucket(float zmax) {
    int k = (int)((1.0f - zmax) * 128.0f);
    return min(max(k, 0), 255);
}

struct FaceSetup {
    float dy12, dx21, x2, y2, dy20, dx02, inv, z0, z1, z2, denom, zmax;
    unsigned int bbx, bby;
};

__device__ __forceinline__ FaceSetup face_setup(const float* __restrict__ tv,
                                                const int* __restrict__ faces,
                                                int b, int f) {
    int i0 = faces[3 * f + 0], i1 = faces[3 * f + 1], i2 = faces[3 * f + 2];
    const float* base = tv + (size_t)b * NV * 3;
    float x0 = base[3 * i0 + 0], y0 = base[3 * i0 + 1], z0 = base[3 * i0 + 2];
    float x1 = base[3 * i1 + 0], y1 = base[3 * i1 + 1], z1 = base[3 * i1 + 2];
    float x2 = base[3 * i2 + 0], y2 = base[3 * i2 + 1], z2 = base[3 * i2 + 2];

    FaceSetup r;
    r.dy12 = __fsub_rn(y1, y2);
    r.dx21 = __fsub_rn(x2, x1);
    r.dy20 = __fsub_rn(y2, y0);
    r.dx02 = __fsub_rn(x0, x2);
    r.denom = __fadd_rn(__fmul_rn(r.dy12, __fsub_rn(x0, x2)),
                        __fmul_rn(r.dx21, __fsub_rn(y0, y2)));
    bool valid = fabsf(r.denom) > 1e-8f;

    int xlo = 1, xhi = 0, ylo = 1, yhi = 0;
    if (valid) {
        if (fabsf(r.denom) < 1e-3f) {
            xlo = 0; xhi = 255; ylo = 0; yhi = 255;
        } else {
            float xmn = fminf(x0, fminf(x1, x2)), xmx = fmaxf(x0, fmaxf(x1, x2));
            float ymn = fminf(y0, fminf(y1, y2)), ymx = fmaxf(y0, fmaxf(y1, y2));
            xlo = (int)floorf((xmn + 1.0f) * 128.0f - 0.5f) - 1;
            xhi = (int)ceilf ((xmx + 1.0f) * 128.0f - 0.5f) + 1;
            ylo = (int)floorf((ymn + 1.0f) * 128.0f - 0.5f) - 1;
            yhi = (int)ceilf ((ymx + 1.0f) * 128.0f - 0.5f) + 1;
            xlo = max(xlo, 0); ylo = max(ylo, 0);
            xhi = min(xhi, 255); yhi = min(yhi, 255);
            if (xhi < xlo || yhi < ylo) { xlo = 1; xhi = 0; ylo = 1; yhi = 0; }
        }
    }
    r.x2 = x2; r.y2 = y2;
    r.inv = valid ? (1.0f / r.denom) : 0.0f;
    r.z0 = z0; r.z1 = z1; r.z2 = z2;
    r.zmax = valid ? fmaxf(z0, fmaxf(z1, z2)) : -2.0f;
    r.bbx = (unsigned)xlo | ((unsigned)xhi << 16);
    r.bby = (unsigned)ylo | ((unsigned)yhi << 16);
    return r;
}

// K1 (regular launch, 16 blocks x 1024):
//   blocks 0-1   : per-batch: setup(in-reg, 2/thread) -> LDS hist -> scan -> scatter
//   blocks 2-11  : per-vertex attributes
//   blocks 12-15 : face setup -> frP (for shade gathers; independent)
__global__ __launch_bounds__(1024) void k_prep(const float* __restrict__ verts,
                                               const float* __restrict__ tex,
                                               const float* __restrict__ uv,
                                               const float* __restrict__ tv,
                                               const int* __restrict__ faces,
                                               float* __restrict__ frP,
                                               float* __restrict__ vattr,
                                               float* __restrict__ rFace) {
    int blk = blockIdx.x, tid = threadIdx.x;

    if (blk >= 2 && blk <= 11) {          // ---- per-vertex attributes ----
        int i = (blk - 2) * 1024 + tid;
        if (i >= NB * NV) return;
        int b = i / NV, v = i - b * NV;
        float u = __fmul_rn(uv[2 * v + 0], 255.0f);
        float w = __fmul_rn(uv[2 * v + 1], 255.0f);
        float uf = floorf(u); uf = fminf(fmaxf(uf, 0.0f), 254.0f);
        float vf = floorf(w); vf = fminf(fmaxf(vf, 0.0f), 254.0f);
        int u0 = (int)uf, v0 = (int)vf;
        float fu = __fsub_rn(u, uf);
        float fv = __fsub_rn(w, vf);
        const float* tx  = tex + (size_t)b * HWD * HWD * 3;
        const float* c00 = tx + ((size_t)v0 * HWD + u0) * 3;
        const float* c01 = c00 + 3;
        const float* c10 = c00 + HWD * 3;
        const float* c11 = c10 + 3;
        float gu = 1.0f - fu, gv = 1.0f - fv;
        float* o = vattr + (size_t)i * 6;
        for (int c = 0; c < 3; ++c) {
            float l0 = c00[c] * gu + c01[c] * fu;
            float l1 = c10[c] * gu + c11[c] * fu;
            o[c] = l0 * gv + l1 * fv;
        }
        const float* vp = verts + ((size_t)b * NV + v) * 3;
        o[3] = vp[0]; o[4] = vp[1]; o[5] = vp[2];
        return;
    }

    if (blk >= 12) {                      // ---- frP for shade (parallel) ----
        int i = (blk - 12) * 1024 + tid;
        if (i >= NB * NF) return;
        int b = i >> 11, f = i & (NF - 1);
        FaceSetup r = face_setup(tv, faces, b, f);
        float* o = frP + (size_t)i * 16;
        o[0] = r.dy12; o[1] = r.dx21; o[2] = r.x2; o[3] = r.y2;
        o[4] = r.dy20; o[5] = r.dx02; o[6] = r.inv; o[7] = r.z0;
        o[8] = r.z1; o[9] = r.z2;
        ((unsigned int*)o)[10] = r.bbx;
        ((unsigned int*)o)[11] = r.bby;
        o[12] = r.denom; o[13] = r.zmax;
        return;
    }

    // ---- blocks 0/1: batch blk — setup in regs -> hist -> scan -> scatter ----
    int b = blk;
    __shared__ unsigned int a[256];
    __shared__ unsigned int cur[256];
    if (tid < 256) a[tid] = 0;
    __syncthreads();

    FaceSetup rec[2];
    int myk[2];
    #pragma unroll
    for (int q = 0; q < 2; ++q) {
        int f = q * 1024 + tid;
        rec[q] = face_setup(tv, faces, b, f);
        myk[q] = z_bucket(rec[q].zmax);
        atomicAdd(&a[myk[q]], 1u);
    }
    __syncthreads();

    unsigned int v = (tid < 256) ? a[tid] : 0u;
    for (int off = 1; off < 256; off <<= 1) {
        unsigned int tt = (tid < 256 && tid >= off) ? a[tid - off] : 0u;
        __syncthreads();
        if (tid < 256) a[tid] += tt;
        __syncthreads();
    }
    if (tid < 256) cur[tid] = a[tid] - v;   // exclusive scan
    __syncthreads();

    #pragma unroll
    for (int q = 0; q < 2; ++q) {
        int fid = q * 1024 + tid;
        unsigned int rank = atomicAdd(&cur[myk[q]], 1u);
        unsigned int slot = (rank & 7u) * 256u + (rank >> 3);  // segment-major
        float* rf = rFace + (((size_t)b * NF + slot) << 4);
        bool skip = fabsf(rec[q].denom) < 1e-3f;
        ((unsigned int*)rf)[0] = rec[q].bbx;
        ((unsigned int*)rf)[1] = rec[q].bby;
        rf[2] = __uint_as_float((unsigned)fid | ((unsigned)skip << 16));
        rf[3] = 1.0f - (float)myk[q] * 0.0078125f + 1e-6f;   // ubound >= bucket zmax
        rf[4] = rec[q].dy12; rf[5] = rec[q].dx21; rf[6] = rec[q].x2; rf[7] = rec[q].y2;
        rf[8] = rec[q].dy20; rf[9] = rec[q].dx02; rf[10] = rec[q].inv; rf[11] = rec[q].z0;
        rf[12] = rec[q].z1; rf[13] = rec[q].z2; rf[14] = 0.0f; rf[15] = 0.0f;
    }
}

// K2: block = (b, 8x8 quad); 8 waves, wave s = segment s. Self-bin + raster
// wave-local (no barriers), register prefetch of next chunk, LDS combine,
// shade distributed across all 8 waves.
__global__ __launch_bounds__(512) void k_raster(const float* __restrict__ rFace,
                                                const float* __restrict__ frP,
                                                const int* __restrict__ faces,
                                                const float* __restrict__ vattr,
                                                float* __restrict__ out) {
    int bid  = blockIdx.x;
    int quad = bid & 1023;
    int b    = bid >> 10;
    int tid = threadIdx.x, seg = tid >> 6, lane = tid & 63;
    int px0 = (quad & 31) << 3, py0 = (quad >> 5) << 3;

    __shared__ __align__(16) float fdat[8][64 * 12];   // 24 KiB
    __shared__ unsigned long long wbest[8][64];        // 4 KiB

    int px = px0 + (lane & 7), py = py0 + (lane >> 3);
    float pxf = pix_coord(px), pyf = pix_coord(py);
    float x0n = pix_coord(px0), x1n = pix_coord(px0 + 7);
    float y0n = pix_coord(py0), y1n = pix_coord(py0 + 7);

    const float* rB = rFace + (((size_t)b * NF) << 4);
    float* myf = fdat[seg];

    unsigned long long best = 0ull;
    float curz = -1.0f;
    bool fin = false;

    // prefetch chunk 0
    const float4* src = (const float4*)(rB + ((size_t)((seg << 8) + lane) << 4));
    float4 h = src[0], g0 = src[1], g1 = src[2], g2 = src[3];

    for (int chunk = 0; chunk < 4 && !fin; ++chunk) {
        unsigned int bbx = __float_as_uint(h.x), bby = __float_as_uint(h.y);
        int xlo = (int)(bbx & 0xffffu), xhi = (int)(bbx >> 16);
        int ylo = (int)(bby & 0xffffu), yhi = (int)(bby >> 16);
        bool keep = (xhi >= xlo) && (xlo <= px0 + 7) && (xhi >= px0)
                                 && (ylo <= py0 + 7) && (yhi >= py0);
        bool skip = (__float_as_uint(h.z) >> 16) != 0u;
        if (keep && !skip) {
            float inv = g1.z, x2 = g0.z, y2 = g0.w;
            float A0 = g0.x * inv, B0 = g0.y * inv;
            float A1 = g1.x * inv, B1 = g1.y * inv;
            float C = A0 + A1, D = B0 + B1;
            float w0m = A0 * ((A0 > 0.f ? x1n : x0n) - x2) + B0 * ((B0 > 0.f ? y1n : y0n) - y2);
            float w1m = A1 * ((A1 > 0.f ? x1n : x0n) - x2) + B1 * ((B1 > 0.f ? y1n : y0n) - y2);
            float w2m = 1.0f - (C * ((C > 0.f ? x0n : x1n) - x2) + D * ((D > 0.f ? y0n : y1n) - y2));
            keep = (w0m >= -5e-3f) && (w1m >= -5e-3f) && (w2m >= -5e-3f);
        }
        unsigned long long mask = __ballot(keep);
        if (keep) {
            int pos = __popcll(mask & ((1ull << lane) - 1ull));
            float* dst = myf + pos * 12;
            ((float4*)dst)[0] = g0;                                  // dy12,dx21,x2,y2
            ((float4*)dst)[1] = g1;                                  // dy20,dx02,inv,z0
            ((float4*)dst)[2] = make_float4(g2.x, g2.y, h.z, h.w);   // z1,z2,fidbits,ub
        }
        int n = (int)__popcll(mask);

        // prefetch next chunk (independent of serial loop below)
        if (chunk < 3) {
            const float4* s2 = (const float4*)(rB +
                ((size_t)((seg << 8) + ((chunk + 1) << 6) + lane) << 4));
            h = s2[0]; g0 = s2[1]; g1 = s2[2]; g2 = s2[3];
        }

        for (int j = 0; j < n; ++j) {
            int base = j * 12;
            if ((j & 3) == 0) {
                float m = curz;
                #pragma unroll
                for (int off = 1; off < 64; off <<= 1) m = fminf(m, __shfl_xor(m, off));
                if (myf[base + 11] < m - 1e-5f) { fin = true; break; }
            }
            const float4 q0 = *(const float4*)(myf + base);
            const float4 q1 = *(const float4*)(myf + base + 4);
            const float4 q2 = *(const float4*)(myf + base + 8);
            float t0 = __fsub_rn(pxf, q0.z);
            float t1 = __fsub_rn(pyf, q0.w);
            float w0 = __fmul_rn(__fadd_rn(__fmul_rn(q0.x, t0), __fmul_rn(q0.y, t1)), q1.z);
            float w1 = __fmul_rn(__fadd_rn(__fmul_rn(q1.x, t0), __fmul_rn(q1.y, t1)), q1.z);
            float w2 = __fsub_rn(__fsub_rn(1.0f, w0), w1);
            if (w0 >= 0.0f && w1 >= 0.0f && w2 >= 0.0f) {
                float z = __fadd_rn(__fadd_rn(__fmul_rn(w0, q1.w), __fmul_rn(w1, q2.x)),
                                    __fmul_rn(w2, q2.y));
                unsigned int fid = __float_as_uint(q2.z) & 0xFFFFu;
                unsigned int ub32 = __float_as_uint(z);
                unsigned int hi = ub32 ^ ((unsigned int)(((int)ub32) >> 31) | 0x80000000u);
                unsigned long long key = ((unsigned long long)hi << 32)
                                       | (unsigned long long)(0x7FFFFFFFu - fid);
                if (key > best) { best = key; curz = z; }
            }
        }
    }

    wbest[seg][lane] = best;
    __syncthreads();

    // ---- distributed combine + shade: every wave combines its lane's pixel;
    //      waves 0-5 store img channel seg, wave 6 alpha+fid, wave 7 zbuf.
    best = wbest[0][lane];
    #pragma unroll
    for (int s = 1; s < 8; ++s) {
        unsigned long long k2 = wbest[s][lane];
        best = (k2 > best) ? k2 : best;
    }

    const size_t plane = (size_t)HWD * HWD;
    int ppix = py * HWD + px;
    int i = (b << 16) + ppix;

    if (best == 0ull) {
        if (seg < 6)      out[((size_t)b * 6 + seg) * plane + ppix] = 0.0f;
        else if (seg == 6) { out[786432 + i] = 0.0f; out[917504 + i] = -1.0f; }
        else               out[1048576 + i] = -1.0f;
        return;
    }

    int f = (int)(0x7FFFFFFFu - (unsigned int)best);
    if (seg == 7) {
        unsigned int hi = (unsigned int)(best >> 32);
        unsigned int zb32 = (hi & 0x80000000u) ? (hi & 0x7FFFFFFFu) : ~hi;
        out[1048576 + i] = __uint_as_float(zb32);
        return;
    }
    if (seg == 6) {
        out[786432 + i] = 1.0f;
        out[917504 + i] = (float)f;
        return;
    }

    // seg 0..5: img channel seg
    const float* fp = frP + (((size_t)(b * NF + f)) << 4);
    float t0 = __fsub_rn(pxf, fp[2]);
    float t1 = __fsub_rn(pyf, fp[3]);
    float w0 = __fmul_rn(__fadd_rn(__fmul_rn(fp[0], t0), __fmul_rn(fp[1], t1)), fp[6]);
    float w1 = __fmul_rn(__fadd_rn(__fmul_rn(fp[4], t0), __fmul_rn(fp[5], t1)), fp[6]);
    float w2 = __fsub_rn(__fsub_rn(1.0f, w0), w1);
    int i0 = faces[3 * f + 0], i1 = faces[3 * f + 1], i2 = faces[3 * f + 2];
    float a0 = vattr[((size_t)b * NV + i0) * 6 + seg];
    float a1 = vattr[((size_t)b * NV + i1) * 6 + seg];
    float a2 = vattr[((size_t)b * NV + i2) * 6 + seg];
    float img = __fadd_rn(__fadd_rn(__fmul_rn(w0, a0), __fmul_rn(w1, a1)),
                          __fmul_rn(w2, a2));
    out[((size_t)b * 6 + seg) * plane + ppix] = img;
}

extern "C" void kernel_launch(void* const* d_in, const int* in_sizes, int n_in,
                              void* d_out, int out_size, void* d_ws, size_t ws_size,
                              hipStream_t stream) {
    (void)in_sizes; (void)n_in; (void)out_size; (void)ws_size;
    const float* verts = (const float*)d_in[0];
    const float* tv    = (const float*)d_in[1];
    const float* tex   = (const float*)d_in[2];
    const float* uv    = (const float*)d_in[3];
    const int*   faces = (const int*)d_in[4];
    float* out = (float*)d_out;

    char* ws = (char*)d_ws;
    float* frP   = (float*)ws;                       // 256 KiB
    float* vattr = (float*)(ws + 0x040000);          // 256 KiB
    float* rFace = (float*)(ws + 0x080000);          // 256 KiB

    k_prep  <<<16, 1024, 0, stream>>>(verts, tex, uv, tv, faces, frP, vattr, rFace);
    k_raster<<<NB * 1024, 512, 0, stream>>>(rFace, frP, faces, vattr, out);
}

// Round 16
// 109.880 us; speedup vs baseline: 1.0543x; 1.0543x over previous
//
#include <hip/hip_runtime.h>

#define HWD 256
#define NB 2
#define NV 5023
#define NF 2048

// ws layout:
//  frP   @ 0x000000  4096 * 64B = 256 KiB  (16 floats per face, batch-major; shade)
//  vattr @ 0x040000  10046*6*4B = 236 KiB  (region 256 KiB)
//  rFace @ 0x080000  4096 * 48B = 192 KiB  (bucket-ordered, segment-major, packed)

__device__ __forceinline__ float pix_coord(int i) {
    return ((float)i + 0.5f) * 0.0078125f - 1.0f;   // exact fp32
}

__device__ __forceinline__ int z_bucket(float zmax) {
    int k = (int)((1.0f - zmax) * 128.0f);
    return min(max(k, 0), 255);
}

struct FaceSetup {
    float dy12, dx21, x2, y2, dy20, dx02, inv, z0, z1, z2, denom, zmax;
    unsigned int bbx, bby;
};

__device__ __forceinline__ FaceSetup face_setup(const float* __restrict__ tv,
                                                const int* __restrict__ faces,
                                                int b, int f) {
    int i0 = faces[3 * f + 0], i1 = faces[3 * f + 1], i2 = faces[3 * f + 2];
    const float* base = tv + (size_t)b * NV * 3;
    float x0 = base[3 * i0 + 0], y0 = base[3 * i0 + 1], z0 = base[3 * i0 + 2];
    float x1 = base[3 * i1 + 0], y1 = base[3 * i1 + 1], z1 = base[3 * i1 + 2];
    float x2 = base[3 * i2 + 0], y2 = base[3 * i2 + 1], z2 = base[3 * i2 + 2];

    FaceSetup r;
    r.dy12 = __fsub_rn(y1, y2);
    r.dx21 = __fsub_rn(x2, x1);
    r.dy20 = __fsub_rn(y2, y0);
    r.dx02 = __fsub_rn(x0, x2);
    r.denom = __fadd_rn(__fmul_rn(r.dy12, __fsub_rn(x0, x2)),
                        __fmul_rn(r.dx21, __fsub_rn(y0, y2)));
    bool valid = fabsf(r.denom) > 1e-8f;

    int xlo = 1, xhi = 0, ylo = 1, yhi = 0;
    if (valid) {
        if (fabsf(r.denom) < 1e-3f) {
            xlo = 0; xhi = 255; ylo = 0; yhi = 255;
        } else {
            float xmn = fminf(x0, fminf(x1, x2)), xmx = fmaxf(x0, fmaxf(x1, x2));
            float ymn = fminf(y0, fminf(y1, y2)), ymx = fmaxf(y0, fmaxf(y1, y2));
            xlo = (int)floorf((xmn + 1.0f) * 128.0f - 0.5f) - 1;
            xhi = (int)ceilf ((xmx + 1.0f) * 128.0f - 0.5f) + 1;
            ylo = (int)floorf((ymn + 1.0f) * 128.0f - 0.5f) - 1;
            yhi = (int)ceilf ((ymx + 1.0f) * 128.0f - 0.5f) + 1;
            xlo = max(xlo, 0); ylo = max(ylo, 0);
            xhi = min(xhi, 255); yhi = min(yhi, 255);
            if (xhi < xlo || yhi < ylo) { xlo = 1; xhi = 0; ylo = 1; yhi = 0; }
        }
    }
    r.x2 = x2; r.y2 = y2;
    r.inv = valid ? (1.0f / r.denom) : 0.0f;
    r.z0 = z0; r.z1 = z1; r.z2 = z2;
    r.zmax = valid ? fmaxf(z0, fmaxf(z1, z2)) : -2.0f;
    r.bbx = (unsigned)xlo | ((unsigned)xhi << 16);
    r.bby = (unsigned)ylo | ((unsigned)yhi << 16);
    return r;
}

// rFace packed record (12 floats / 48 B):
//  [0] bb   = xlo | xhi<<8 | ylo<<16 | yhi<<24   (u32)
//  [1] meta = fid | k<<11 | skip<<19             (u32)
//  [2..11] dy12, dx21, x2, y2, dy20, dx02, inv, z0, z1, z2

// K1 (regular launch, 16 blocks x 1024):
//   blocks 0-1   : per-batch: setup(in-reg, 2/thread) -> LDS hist -> scan -> scatter
//   blocks 2-11  : per-vertex attributes
//   blocks 12-15 : face setup -> frP (for shade gathers; independent)
__global__ __launch_bounds__(1024) void k_prep(const float* __restrict__ verts,
                                               const float* __restrict__ tex,
                                               const float* __restrict__ uv,
                                               const float* __restrict__ tv,
                                               const int* __restrict__ faces,
                                               float* __restrict__ frP,
                                               float* __restrict__ vattr,
                                               float* __restrict__ rFace) {
    int blk = blockIdx.x, tid = threadIdx.x;

    if (blk >= 2 && blk <= 11) {          // ---- per-vertex attributes ----
        int i = (blk - 2) * 1024 + tid;
        if (i >= NB * NV) return;
        int b = i / NV, v = i - b * NV;
        float u = __fmul_rn(uv[2 * v + 0], 255.0f);
        float w = __fmul_rn(uv[2 * v + 1], 255.0f);
        float uf = floorf(u); uf = fminf(fmaxf(uf, 0.0f), 254.0f);
        float vf = floorf(w); vf = fminf(fmaxf(vf, 0.0f), 254.0f);
        int u0 = (int)uf, v0 = (int)vf;
        float fu = __fsub_rn(u, uf);
        float fv = __fsub_rn(w, vf);
        const float* tx  = tex + (size_t)b * HWD * HWD * 3;
        const float* c00 = tx + ((size_t)v0 * HWD + u0) * 3;
        const float* c01 = c00 + 3;
        const float* c10 = c00 + HWD * 3;
        const float* c11 = c10 + 3;
        float gu = 1.0f - fu, gv = 1.0f - fv;
        float* o = vattr + (size_t)i * 6;
        for (int c = 0; c < 3; ++c) {
            float l0 = c00[c] * gu + c01[c] * fu;
            float l1 = c10[c] * gu + c11[c] * fu;
            o[c] = l0 * gv + l1 * fv;
        }
        const float* vp = verts + ((size_t)b * NV + v) * 3;
        o[3] = vp[0]; o[4] = vp[1]; o[5] = vp[2];
        return;
    }

    if (blk >= 12) {                      // ---- frP for shade (parallel) ----
        int i = (blk - 12) * 1024 + tid;
        if (i >= NB * NF) return;
        int b = i >> 11, f = i & (NF - 1);
        FaceSetup r = face_setup(tv, faces, b, f);
        float* o = frP + (size_t)i * 16;
        o[0] = r.dy12; o[1] = r.dx21; o[2] = r.x2; o[3] = r.y2;
        o[4] = r.dy20; o[5] = r.dx02; o[6] = r.inv; o[7] = r.z0;
        o[8] = r.z1; o[9] = r.z2;
        ((unsigned int*)o)[10] = r.bbx;
        ((unsigned int*)o)[11] = r.bby;
        o[12] = r.denom; o[13] = r.zmax;
        return;
    }

    // ---- blocks 0/1: batch blk — setup in regs -> hist -> scan -> scatter ----
    int b = blk;
    __shared__ unsigned int a[256];
    __shared__ unsigned int cur[256];
    if (tid < 256) a[tid] = 0;
    __syncthreads();

    FaceSetup rec[2];
    int myk[2];
    #pragma unroll
    for (int q = 0; q < 2; ++q) {
        int f = q * 1024 + tid;
        rec[q] = face_setup(tv, faces, b, f);
        myk[q] = z_bucket(rec[q].zmax);
        atomicAdd(&a[myk[q]], 1u);
    }
    __syncthreads();

    unsigned int v = (tid < 256) ? a[tid] : 0u;
    for (int off = 1; off < 256; off <<= 1) {
        unsigned int tt = (tid < 256 && tid >= off) ? a[tid - off] : 0u;
        __syncthreads();
        if (tid < 256) a[tid] += tt;
        __syncthreads();
    }
    if (tid < 256) cur[tid] = a[tid] - v;   // exclusive scan
    __syncthreads();

    #pragma unroll
    for (int q = 0; q < 2; ++q) {
        int fid = q * 1024 + tid;
        unsigned int rank = atomicAdd(&cur[myk[q]], 1u);
        unsigned int slot = (rank & 7u) * 256u + (rank >> 3);  // segment-major
        float* rf = rFace + (size_t)(b * NF + slot) * 12;
        unsigned int skip = (fabsf(rec[q].denom) < 1e-3f) ? 1u : 0u;
        unsigned int xlo = rec[q].bbx & 0xffu, xhi = (rec[q].bbx >> 16) & 0xffu;
        unsigned int ylo = rec[q].bby & 0xffu, yhi = (rec[q].bby >> 16) & 0xffu;
        ((unsigned int*)rf)[0] = xlo | (xhi << 8) | (ylo << 16) | (yhi << 24);
        ((unsigned int*)rf)[1] = (unsigned)fid | ((unsigned)myk[q] << 11) | (skip << 19);
        rf[2] = rec[q].dy12; rf[3] = rec[q].dx21; rf[4] = rec[q].x2; rf[5] = rec[q].y2;
        rf[6] = rec[q].dy20; rf[7] = rec[q].dx02; rf[8] = rec[q].inv; rf[9] = rec[q].z0;
        rf[10] = rec[q].z1; rf[11] = rec[q].z2;
    }
}

// K2: block = (b, 8x8 quad); 8 waves, wave s = segment s. Self-bin + raster
// wave-local (no barriers), LDS combine, wave 0 shades. No global z-buffer.
__global__ __launch_bounds__(512) void k_raster(const float* __restrict__ rFace,
                                                const float* __restrict__ frP,
                                                const int* __restrict__ faces,
                                                const float* __restrict__ vattr,
                                                float* __restrict__ out) {
    int bid  = blockIdx.x;
    int quad = bid & 1023;
    int b    = bid >> 10;
    int tid = threadIdx.x, seg = tid >> 6, lane = tid & 63;
    int px0 = (quad & 31) << 3, py0 = (quad >> 5) << 3;

    __shared__ __align__(16) float fdat[8][64 * 12];   // 24 KiB
    __shared__ unsigned long long wbest[8][64];        // 4 KiB

    int px = px0 + (lane & 7), py = py0 + (lane >> 3);
    float pxf = pix_coord(px), pyf = pix_coord(py);
    float x0n = pix_coord(px0), x1n = pix_coord(px0 + 7);
    float y0n = pix_coord(py0), y1n = pix_coord(py0 + 7);

    const float* rB = rFace + (size_t)b * NF * 12;
    float* myf = fdat[seg];

    unsigned long long best = 0ull;
    float curz = -1.0f;
    bool fin = false;

    for (int chunk = 0; chunk < 4 && !fin; ++chunk) {
        int slot = (seg << 8) + (chunk << 6) + lane;
        const float4* src = (const float4*)(rB + (size_t)slot * 12);
        float4 s0 = src[0], s1 = src[1], s2 = src[2];
        // s0 = bb, meta, dy12, dx21 ; s1 = x2, y2, dy20, dx02 ; s2 = inv, z0, z1, z2
        unsigned int bb   = __float_as_uint(s0.x);
        unsigned int meta = __float_as_uint(s0.y);
        int xlo = (int)(bb & 0xffu),        xhi = (int)((bb >> 8) & 0xffu);
        int ylo = (int)((bb >> 16) & 0xffu), yhi = (int)(bb >> 24);
        bool keep = (xhi >= xlo) && (xlo <= px0 + 7) && (xhi >= px0)
                                 && (ylo <= py0 + 7) && (yhi >= py0);
        bool skip = (meta >> 19) != 0u;
        if (keep && !skip) {
            float inv = s2.x, x2 = s1.x, y2 = s1.y;
            float A0 = s0.z * inv, B0 = s0.w * inv;
            float A1 = s1.z * inv, B1 = s1.w * inv;
            float C = A0 + A1, D = B0 + B1;
            float w0m = A0 * ((A0 > 0.f ? x1n : x0n) - x2) + B0 * ((B0 > 0.f ? y1n : y0n) - y2);
            float w1m = A1 * ((A1 > 0.f ? x1n : x0n) - x2) + B1 * ((B1 > 0.f ? y1n : y0n) - y2);
            float w2m = 1.0f - (C * ((C > 0.f ? x0n : x1n) - x2) + D * ((D > 0.f ? y0n : y1n) - y2));
            keep = (w0m >= -5e-3f) && (w1m >= -5e-3f) && (w2m >= -5e-3f);
        }
        unsigned long long mask = __ballot(keep);
        if (keep) {
            int k = (int)((meta >> 11) & 0xffu);
            // ub >= bucket sup: 1 - k/128 exact in fp32; +1e-6 absorbs z_bucket rounding
            float ub = __fadd_rn(__fsub_rn(1.0f, __fmul_rn((float)k, 0.0078125f)), 1e-6f);
            int pos = __popcll(mask & ((1ull << lane) - 1ull));
            float* dst = myf + pos * 12;
            ((float4*)dst)[0] = make_float4(s0.z, s0.w, s1.x, s1.y);   // dy12,dx21,x2,y2
            ((float4*)dst)[1] = make_float4(s1.z, s1.w, s2.x, s2.y);   // dy20,dx02,inv,z0
            ((float4*)dst)[2] = make_float4(s2.z, s2.w,
                __uint_as_float(meta & 0x7FFu), ub);                    // z1,z2,fid,ub
        }
        int n = (int)__popcll(mask);

        for (int j = 0; j < n; ++j) {
            int base = j * 12;
            if ((j & 7) == 0) {
                float m = curz;
                #pragma unroll
                for (int off = 1; off < 64; off <<= 1) m = fminf(m, __shfl_xor(m, off));
                if (myf[base + 11] < m - 1e-5f) { fin = true; break; }
            }
            const float4 q0 = *(const float4*)(myf + base);
            const float4 q1 = *(const float4*)(myf + base + 4);
            const float4 q2 = *(const float4*)(myf + base + 8);
            float t0 = __fsub_rn(pxf, q0.z);
            float t1 = __fsub_rn(pyf, q0.w);
            float w0 = __fmul_rn(__fadd_rn(__fmul_rn(q0.x, t0), __fmul_rn(q0.y, t1)), q1.z);
            float w1 = __fmul_rn(__fadd_rn(__fmul_rn(q1.x, t0), __fmul_rn(q1.y, t1)), q1.z);
            float w2 = __fsub_rn(__fsub_rn(1.0f, w0), w1);
            if (w0 >= 0.0f && w1 >= 0.0f && w2 >= 0.0f) {
                float z = __fadd_rn(__fadd_rn(__fmul_rn(w0, q1.w), __fmul_rn(w1, q2.x)),
                                    __fmul_rn(w2, q2.y));
                unsigned int fid = __float_as_uint(q2.z) & 0xFFFFu;
                unsigned int ub32 = __float_as_uint(z);
                unsigned int hi = ub32 ^ ((unsigned int)(((int)ub32) >> 31) | 0x80000000u);
                unsigned long long key = ((unsigned long long)hi << 32)
                                       | (unsigned long long)(0x7FFFFFFFu - fid);
                if (key > best) { best = key; curz = z; }
            }
        }
    }

    wbest[seg][lane] = best;
    __syncthreads();

    // ---- wave 0: combine + shade ----
    if (tid >= 64) return;
    best = wbest[0][lane];
    #pragma unroll
    for (int s = 1; s < 8; ++s) {
        unsigned long long k2 = wbest[s][lane];
        best = (k2 > best) ? k2 : best;
    }

    float img[6] = {0, 0, 0, 0, 0, 0};
    float alpha, fidf, zout;
    if (best == 0ull) {
        alpha = 0.0f; fidf = -1.0f; zout = -1.0f;
    } else {
        int f = (int)(0x7FFFFFFFu - (unsigned int)best);
        unsigned int hi = (unsigned int)(best >> 32);
        unsigned int zb32 = (hi & 0x80000000u) ? (hi & 0x7FFFFFFFu) : ~hi;
        zout = __uint_as_float(zb32);
        alpha = 1.0f;
        fidf = (float)f;
        const float* fp = frP + (((size_t)(b * NF + f)) << 4);
        float t0 = __fsub_rn(pxf, fp[2]);
        float t1 = __fsub_rn(pyf, fp[3]);
        float w0 = __fmul_rn(__fadd_rn(__fmul_rn(fp[0], t0), __fmul_rn(fp[1], t1)), fp[6]);
        float w1 = __fmul_rn(__fadd_rn(__fmul_rn(fp[4], t0), __fmul_rn(fp[5], t1)), fp[6]);
        float w2 = __fsub_rn(__fsub_rn(1.0f, w0), w1);
        int i0 = faces[3 * f + 0], i1 = faces[3 * f + 1], i2 = faces[3 * f + 2];
        const float* a0 = vattr + ((size_t)b * NV + i0) * 6;
        const float* a1 = vattr + ((size_t)b * NV + i1) * 6;
        const float* a2 = vattr + ((size_t)b * NV + i2) * 6;
        for (int c = 0; c < 6; ++c)
            img[c] = __fadd_rn(__fadd_rn(__fmul_rn(w0, a0[c]), __fmul_rn(w1, a1[c])),
                               __fmul_rn(w2, a2[c]));
    }

    const size_t plane = (size_t)HWD * HWD;
    int ppix = py * HWD + px;
    int i = (b << 16) + ppix;
    for (int c = 0; c < 6; ++c)
        out[((size_t)b * 6 + c) * plane + ppix] = img[c];
    out[786432 + i]  = alpha;
    out[917504 + i]  = fidf;
    out[1048576 + i] = zout;
}

extern "C" void kernel_launch(void* const* d_in, const int* in_sizes, int n_in,
                              void* d_out, int out_size, void* d_ws, size_t ws_size,
                              hipStream_t stream) {
    (void)in_sizes; (void)n_in; (void)out_size; (void)ws_size;
    const float* verts = (const float*)d_in[0];
    const float* tv    = (const float*)d_in[1];
    const float* tex   = (const float*)d_in[2];
    const float* uv    = (const float*)d_in[3];
    const int*   faces = (const int*)d_in[4];
    float* out = (float*)d_out;

    char* ws = (char*)d_ws;
    float* frP   = (float*)ws;                       // 256 KiB
    float* vattr = (float*)(ws + 0x040000);          // 256 KiB
    float* rFace = (float*)(ws + 0x080000);          // 192 KiB

    k_prep  <<<16, 1024, 0, stream>>>(verts, tex, uv, tv, faces, frP, vattr, rFace);
    k_raster<<<NB * 1024, 512, 0, stream>>>(rFace, frP, faces, vattr, out);
}